// Round 1
// baseline (20.909 us; speedup 1.0000x reference)
//
#include <hip/hip_runtime.h>
#include <hip/hip_bf16.h>

// FrameReducer: N=16, T=2048, C=512, V=500 (shapes derived at launch where possible)
//
// Stage 1 (compact_kernel): one block per sequence n.
//   keep[t] = (ctc[n,t,blank] < log(0.9)) && (t < x_lens[n])
//   Compact kept t's (stable, original order) into ws idx[n][0..lens-1]; lens[n] = count.
//   Also writes lens as float into the tail of d_out.
// Stage 2 (gather_kernel): one block per output row (n,p), p in [0,T').
//   out[n,p,:] = (p < lens[n]) ? x[n, idx[n][p], :] : 0   (float4-vectorized)

__global__ void compact_kernel(const float* __restrict__ ctc,
                               const void* __restrict__ x_lens_raw,
                               const int* __restrict__ blank_id_p,
                               int N, int T, int V,
                               int* __restrict__ idx,
                               int* __restrict__ lens,
                               float* __restrict__ lens_out) {
    const int n   = blockIdx.x;
    const int tid = threadIdx.x;            // 256 threads
    const int NTHREADS = 256;
    const int PER = (T + NTHREADS - 1) / NTHREADS;   // 8 for T=2048 (<=32 supported)

    // x_lens dtype detection: values are in [1, T] (never 0). If stored as
    // int64 (little-endian), the int32 view at odd positions is 0.
    const int* li = (const int*)x_lens_raw;
    long long L;
    if (N > 1 && li[1] == 0) {
        L = ((const long long*)x_lens_raw)[n];   // int64 layout
    } else {
        L = (long long)li[n];                    // int32 layout
    }

    const int blank = *blank_id_p;
    const float thr = -0.10536052f;              // float32(log(0.9)), matches jax promotion

    unsigned int keepmask = 0u;
    int cnt = 0;
    const int t0 = tid * PER;
    for (int j = 0; j < PER; ++j) {
        int t = t0 + j;
        if (t < T) {
            float v = ctc[((long long)n * T + t) * V + blank];
            bool k = (v < thr) && ((long long)t < L);
            keepmask |= (k ? (1u << j) : 0u);
            cnt += k ? 1 : 0;
        }
    }

    __shared__ int s[NTHREADS];
    s[tid] = cnt;
    __syncthreads();
    if (tid == 0) {
        int acc = 0;
        for (int i = 0; i < NTHREADS; ++i) { int c = s[i]; s[i] = acc; acc += c; }
        lens[n] = acc;
        lens_out[n] = (float)acc;
    }
    __syncthreads();

    int off = s[tid];
    int* my_idx = idx + (long long)n * T;
    for (int j = 0; j < PER; ++j) {
        if (keepmask & (1u << j)) {
            my_idx[off++] = t0 + j;
        }
    }
}

__global__ void gather_kernel(const float* __restrict__ x,
                              const int* __restrict__ idx,
                              const int* __restrict__ lens,
                              float* __restrict__ out,
                              int Tp, int T, int C) {
    const long long row = blockIdx.x;        // n*Tp + p
    const int n = (int)(row / Tp);
    const int p = (int)(row % Tp);
    const int tid = threadIdx.x;             // C/4 threads (128 for C=512)

    float4 v = make_float4(0.f, 0.f, 0.f, 0.f);
    if (p < lens[n]) {
        int tsrc = idx[(long long)n * T + p];
        const float4* src = (const float4*)(x + ((long long)n * T + tsrc) * C);
        v = src[tid];
    }
    float4* dst = (float4*)(out + row * (long long)C);
    dst[tid] = v;
}

extern "C" void kernel_launch(void* const* d_in, const int* in_sizes, int n_in,
                              void* d_out, int out_size, void* d_ws, size_t ws_size,
                              hipStream_t stream) {
    const float* x        = (const float*)d_in[0];
    const void*  x_lens   = d_in[1];
    const float* ctc      = (const float*)d_in[2];
    const int*   blank_id = (const int*)d_in[3];

    const int N = in_sizes[1];               // 16
    const int C = 512;
    const int V = 500;
    const int T = in_sizes[0] / (N * C);     // 2048
    const int Tp = (out_size - N) / (N * C); // T' (max kept length), fixed by inputs

    int* idx  = (int*)d_ws;                  // [N][T]
    int* lens = idx + (long long)N * T;      // [N]

    float* out      = (float*)d_out;                         // [N][Tp][C]
    float* lens_out = out + (long long)N * Tp * C;           // [N] as float

    compact_kernel<<<N, 256, 0, stream>>>(ctc, x_lens, blank_id, N, T, V, idx, lens, lens_out);
    gather_kernel<<<(unsigned int)(N * Tp), C / 4, 0, stream>>>(x, idx, lens, out, Tp, T, C);
}